// Round 1
// baseline (3155.004 us; speedup 1.0000x reference)
//
#include <hip/hip_runtime.h>
#include <math.h>

typedef __bf16 bf16;
typedef float f32x4 __attribute__((ext_vector_type(4)));
typedef __bf16 bf16x8 __attribute__((ext_vector_type(8)));
typedef __bf16 bf16x4 __attribute__((ext_vector_type(4)));

// ---------------------------------------------------------------- helpers
__device__ __forceinline__ void gld16(const bf16* g, bf16* l)
{
    __builtin_amdgcn_global_load_lds(
        (const __attribute__((address_space(1))) void*)g,
        (__attribute__((address_space(3))) void*)l, 16, 0, 0);
}

__device__ __forceinline__ float gelu_exact(float x)
{
    return 0.5f * x * (1.0f + erff(x * 0.70710678118654752f));
}

// ---------------------------------------------------------------- GEMM
// C[M,N] = A[M,K](bf16,row-major) @ Bt[N,K](bf16,row-major)^T + bias
// EPI: 0 = bf16 out, 1 = gelu->bf16 out, 2 = fp32 residual out, 3 = embed
template <int EPI>
__launch_bounds__(256, 2)
__global__ void gemm_bt(const bf16* __restrict__ A, const bf16* __restrict__ Bt,
                        const float* __restrict__ bias, int K, int N,
                        float* __restrict__ fout, bf16* __restrict__ bout,
                        const float* __restrict__ res, const float* __restrict__ bias2,
                        const float* __restrict__ dvec, const float* __restrict__ wdur)
{
    __shared__ alignas(16) bf16 As[128 * 32];
    __shared__ alignas(16) bf16 Bs[128 * 32];
    const int tid = threadIdx.x;
    const int lane = tid & 63, wave = tid >> 6;
    const int quad = lane >> 4, l16 = lane & 15;
    const int wr = wave >> 1, wc = wave & 1;
    const int mBase = blockIdx.y * 128, nBase = blockIdx.x * 128;

    f32x4 zero = {0.f, 0.f, 0.f, 0.f};
    f32x4 acc[4][4];
#pragma unroll
    for (int i = 0; i < 4; ++i)
#pragma unroll
        for (int j = 0; j < 4; ++j) acc[i][j] = zero;

    const int c0 = wave * 128 + lane;
    const int c1 = c0 + 64;
    const bf16* Ag0 = A + (size_t)(mBase + (c0 >> 2)) * K + (c0 & 3) * 8;
    const bf16* Ag1 = A + (size_t)(mBase + (c1 >> 2)) * K + (c1 & 3) * 8;
    const bf16* Bg0 = Bt + (size_t)(nBase + (c0 >> 2)) * K + (c0 & 3) * 8;
    const bf16* Bg1 = Bt + (size_t)(nBase + (c1 >> 2)) * K + (c1 & 3) * 8;
    // wave-uniform LDS bases; HW writes base + lane*16
    bf16* Al0 = As + (size_t)(wave * 128) * 8;
    bf16* Al1 = As + (size_t)(wave * 128 + 64) * 8;
    bf16* Bl0 = Bs + (size_t)(wave * 128) * 8;
    bf16* Bl1 = Bs + (size_t)(wave * 128 + 64) * 8;

    for (int k0 = 0; k0 < K; k0 += 32) {
        gld16(Ag0 + k0, Al0);
        gld16(Ag1 + k0, Al1);
        gld16(Bg0 + k0, Bl0);
        gld16(Bg1 + k0, Bl1);
        __syncthreads();
        bf16x8 af[4], bfr[4];
#pragma unroll
        for (int t = 0; t < 4; ++t) {
            af[t]  = *(const bf16x8*)(As + (wr * 64 + t * 16 + l16) * 32 + quad * 8);
            bfr[t] = *(const bf16x8*)(Bs + (wc * 64 + t * 16 + l16) * 32 + quad * 8);
        }
#pragma unroll
        for (int i = 0; i < 4; ++i)
#pragma unroll
            for (int j = 0; j < 4; ++j)
                acc[i][j] = __builtin_amdgcn_mfma_f32_16x16x32_bf16(af[i], bfr[j], acc[i][j], 0, 0, 0);
        __syncthreads();
    }

#pragma unroll
    for (int i = 0; i < 4; ++i) {
        const int row0 = mBase + wr * 64 + i * 16 + quad * 4;
#pragma unroll
        for (int j = 0; j < 4; ++j) {
            const int col = nBase + wc * 64 + j * 16 + l16;
            const float bs = bias[col];
#pragma unroll
            for (int r = 0; r < 4; ++r) {
                const int row = row0 + r;
                float v = acc[i][j][r] + bs;
                if (EPI == 0) {
                    bout[(size_t)row * N + col] = (bf16)v;
                } else if (EPI == 1) {
                    bout[(size_t)row * N + col] = (bf16)gelu_exact(v);
                } else if (EPI == 2) {
                    fout[(size_t)row * N + col] = res[(size_t)row * N + col] + v;
                } else {
                    v += bias2[col] + dvec[row] * wdur[col];
                    fout[(size_t)row * N + col] = v;
                }
            }
        }
    }
}

// ---------------------------------------------------------------- LayerNorm -> bf16
__launch_bounds__(256)
__global__ void ln_kernel(const float* __restrict__ x, const float* __restrict__ g,
                          const float* __restrict__ b, bf16* __restrict__ out)
{
    const int row = blockIdx.x, tid = threadIdx.x;
    const int lane = tid & 63, wave = tid >> 6;
    float4 v = ((const float4*)(x + (size_t)row * 1024))[tid];
    float s = v.x + v.y + v.z + v.w;
    float q = v.x * v.x + v.y * v.y + v.z * v.z + v.w * v.w;
#pragma unroll
    for (int o = 32; o > 0; o >>= 1) {
        s += __shfl_down(s, o, 64);
        q += __shfl_down(q, o, 64);
    }
    __shared__ float red[8];
    if (lane == 0) { red[wave] = s; red[4 + wave] = q; }
    __syncthreads();
    s = red[0] + red[1] + red[2] + red[3];
    q = red[4] + red[5] + red[6] + red[7];
    const float mean = s * 0.0009765625f;
    const float var = q * 0.0009765625f - mean * mean;
    const float rstd = rsqrtf(var + 1e-5f);
    float4 gv = ((const float4*)g)[tid];
    float4 bv = ((const float4*)b)[tid];
    bf16x4 o4;
    o4[0] = (bf16)((v.x - mean) * rstd * gv.x + bv.x);
    o4[1] = (bf16)((v.y - mean) * rstd * gv.y + bv.y);
    o4[2] = (bf16)((v.z - mean) * rstd * gv.z + bv.z);
    o4[3] = (bf16)((v.w - mean) * rstd * gv.w + bv.w);
    ((bf16x4*)(out + (size_t)row * 1024))[tid] = o4;
}

// ---------------------------------------------------------------- RoPE (in-place on q,k of qkv)
__launch_bounds__(256)
__global__ void rope_kernel(bf16* __restrict__ qkv)
{
    const int id = blockIdx.x * 256 + threadIdx.x;   // 2048 rows * 2 (q/k) * 16 heads * 32 pairs
    const int i = id & 31;
    const int head = (id >> 5) & 15;
    const int qk = (id >> 9) & 1;
    const int m = id >> 10;
    const int s = m >> 2;                            // m = s*4 + b
    const size_t base = (size_t)m * 3072 + (size_t)qk * 1024 + head * 64 + i;
    const float x1 = (float)qkv[base];
    const float x2 = (float)qkv[base + 32];
    const float inv = expf((float)i * -0.28782313662425574f);  // ln(10000)/32
    const float ang = (float)s * inv;
    const float c = cosf(ang), sn = sinf(ang);
    qkv[base]      = (bf16)(x1 * c - x2 * sn);
    qkv[base + 32] = (bf16)(x2 * c + x1 * sn);
}

// ---------------------------------------------------------------- V^T builder: vT[(b*16+h)*64+d][s]
__launch_bounds__(256)
__global__ void vt_kernel(const bf16* __restrict__ qkv, bf16* __restrict__ vT)
{
    __shared__ bf16 tile[32][33];
    const int tid = threadIdx.x;
    const int tx = tid & 31, ty = tid >> 5;
    const int bh = blockIdx.z, b = bh >> 4, h = bh & 15;
    const int s0 = blockIdx.x * 32, d0 = blockIdx.y * 32;
#pragma unroll
    for (int i = 0; i < 4; ++i) {
        const int s = s0 + ty + i * 8;
        tile[ty + i * 8][tx] = qkv[(size_t)(s * 4 + b) * 3072 + 2048 + h * 64 + d0 + tx];
    }
    __syncthreads();
#pragma unroll
    for (int i = 0; i < 4; ++i) {
        const int d = d0 + ty + i * 8;
        vT[((size_t)(b * 16 + h) * 64 + d) * 512 + s0 + tx] = tile[tx][ty + i * 8];
    }
}

// ---------------------------------------------------------------- fused flash attention
// grid (qt=4, h=16, b=4); block 256 = 4 waves, wave handles 32 q-rows
__launch_bounds__(256, 2)
__global__ void attn_kernel(const bf16* __restrict__ qkv, const bf16* __restrict__ vT,
                            const int* __restrict__ mask, bf16* __restrict__ out)
{
    __shared__ alignas(16) bf16 Ks[64 * 72];       // [kj_local][d], stride 72
    __shared__ alignas(16) bf16 Vts[64 * 72];      // [d][kj_local], stride 72
    __shared__ alignas(16) bf16 Pscr[4][32 * 72];  // per-wave P scratch, stride 72
    __shared__ float mbias[512];

    const int tid = threadIdx.x;
    const int lane = tid & 63, wave = tid >> 6;
    const int quad = lane >> 4, l16 = lane & 15;
    const int qt = blockIdx.x, h = blockIdx.y, b = blockIdx.z;

    for (int i = tid; i < 512; i += 256)
        mbias[i] = mask[b * 512 + i] ? -1e30f : 0.0f;

    bf16x8 qf[2][2];
#pragma unroll
    for (int t = 0; t < 2; ++t)
#pragma unroll
        for (int c = 0; c < 2; ++c) {
            const int s = qt * 128 + wave * 32 + t * 16 + l16;
            qf[t][c] = *(const bf16x8*)(qkv + (size_t)(s * 4 + b) * 3072 + h * 64 + c * 32 + quad * 8);
        }

    f32x4 zero = {0.f, 0.f, 0.f, 0.f};
    f32x4 O[2][4];
    float m_run[2][4], l_run[2][4];
#pragma unroll
    for (int t = 0; t < 2; ++t) {
#pragma unroll
        for (int d = 0; d < 4; ++d) O[t][d] = zero;
#pragma unroll
        for (int r = 0; r < 4; ++r) { m_run[t][r] = -10000.f; l_run[t][r] = 0.f; }
    }

    for (int kt = 0; kt < 8; ++kt) {
        // global loads into regs (K chunk and V^T chunk)
        bf16x8 kreg[2], vreg[2];
#pragma unroll
        for (int i = 0; i < 2; ++i) {
            const int c = wave * 128 + i * 64 + lane;
            const int kr = c >> 3, dc = c & 7;
            kreg[i] = *(const bf16x8*)(qkv + (size_t)((kt * 64 + kr) * 4 + b) * 3072 + 1024 + h * 64 + dc * 8);
            vreg[i] = *(const bf16x8*)(vT + ((size_t)(b * 16 + h) * 64 + kr) * 512 + kt * 64 + dc * 8);
        }
        __syncthreads();   // previous iteration's LDS reads complete
#pragma unroll
        for (int i = 0; i < 2; ++i) {
            const int c = wave * 128 + i * 64 + lane;
            const int kr = c >> 3, dc = c & 7;
            *(bf16x8*)(Ks + kr * 72 + dc * 8)  = kreg[i];
            *(bf16x8*)(Vts + kr * 72 + dc * 8) = vreg[i];
        }
        __syncthreads();   // publish tiles

        // S = Q K^T  (S[q][kj], C-layout: row=quad*4+reg, col=l16)
        bf16x8 bk_[4][2];
#pragma unroll
        for (int tc = 0; tc < 4; ++tc)
#pragma unroll
            for (int c = 0; c < 2; ++c)
                bk_[tc][c] = *(const bf16x8*)(Ks + (tc * 16 + l16) * 72 + c * 32 + quad * 8);

        f32x4 sf[2][4];
#pragma unroll
        for (int t = 0; t < 2; ++t)
#pragma unroll
            for (int tc = 0; tc < 4; ++tc) {
                f32x4 z = zero;
                z = __builtin_amdgcn_mfma_f32_16x16x32_bf16(qf[t][0], bk_[tc][0], z, 0, 0, 0);
                z = __builtin_amdgcn_mfma_f32_16x16x32_bf16(qf[t][1], bk_[tc][1], z, 0, 0, 0);
                sf[t][tc] = z;
            }

#pragma unroll
        for (int t = 0; t < 2; ++t) {
#pragma unroll
            for (int tc = 0; tc < 4; ++tc) {
                const float mb = mbias[kt * 64 + tc * 16 + l16];
#pragma unroll
                for (int r = 0; r < 4; ++r)
                    sf[t][tc][r] = sf[t][tc][r] * 0.125f + mb;
            }
#pragma unroll
            for (int r = 0; r < 4; ++r) {
                float tm = fmaxf(fmaxf(sf[t][0][r], sf[t][1][r]), fmaxf(sf[t][2][r], sf[t][3][r]));
                tm = fmaxf(tm, __shfl_xor(tm, 1, 64));
                tm = fmaxf(tm, __shfl_xor(tm, 2, 64));
                tm = fmaxf(tm, __shfl_xor(tm, 4, 64));
                tm = fmaxf(tm, __shfl_xor(tm, 8, 64));
                const float mn = fmaxf(m_run[t][r], tm);
                const float alpha = __expf(m_run[t][r] - mn);
                m_run[t][r] = mn;
                float rs = 0.f;
#pragma unroll
                for (int tc = 0; tc < 4; ++tc) {
                    const float p = __expf(sf[t][tc][r] - mn);
                    sf[t][tc][r] = p;
                    rs += p;
                }
                rs += __shfl_xor(rs, 1, 64);
                rs += __shfl_xor(rs, 2, 64);
                rs += __shfl_xor(rs, 4, 64);
                rs += __shfl_xor(rs, 8, 64);
                l_run[t][r] = l_run[t][r] * alpha + rs;
#pragma unroll
                for (int d = 0; d < 4; ++d) O[t][d][r] *= alpha;
            }
#pragma unroll
            for (int tc = 0; tc < 4; ++tc)
#pragma unroll
                for (int r = 0; r < 4; ++r)
                    Pscr[wave][(t * 16 + quad * 4 + r) * 72 + tc * 16 + l16] = (bf16)sf[t][tc][r];
        }

        // O += P @ V
        bf16x8 bv_[4][2];
#pragma unroll
        for (int d = 0; d < 4; ++d)
#pragma unroll
            for (int c = 0; c < 2; ++c)
                bv_[d][c] = *(const bf16x8*)(Vts + (d * 16 + l16) * 72 + c * 32 + quad * 8);
#pragma unroll
        for (int t = 0; t < 2; ++t) {
            bf16x8 pa0 = *(const bf16x8*)(&Pscr[wave][(t * 16 + l16) * 72 + quad * 8]);
            bf16x8 pa1 = *(const bf16x8*)(&Pscr[wave][(t * 16 + l16) * 72 + 32 + quad * 8]);
#pragma unroll
            for (int d = 0; d < 4; ++d) {
                O[t][d] = __builtin_amdgcn_mfma_f32_16x16x32_bf16(pa0, bv_[d][0], O[t][d], 0, 0, 0);
                O[t][d] = __builtin_amdgcn_mfma_f32_16x16x32_bf16(pa1, bv_[d][1], O[t][d], 0, 0, 0);
            }
        }
        __syncthreads();
    }

#pragma unroll
    for (int t = 0; t < 2; ++t)
#pragma unroll
        for (int d = 0; d < 4; ++d) {
            const int col = h * 64 + d * 16 + l16;
#pragma unroll
            for (int r = 0; r < 4; ++r) {
                const int s = qt * 128 + wave * 32 + t * 16 + quad * 4 + r;
                out[(size_t)(s * 4 + b) * 1024 + col] = (bf16)(O[t][d][r] / l_run[t][r]);
            }
        }
}

// ---------------------------------------------------------------- weight transpose fp32 -> bf16^T
__device__ __forceinline__ void trans_tile32(const float* __restrict__ src, bf16* __restrict__ dst,
                                             int R, int C, int r0, int c0, int tid)
{
    __shared__ float tile[32][33];
    const int tx = tid & 31, ty = tid >> 5;
#pragma unroll
    for (int i = 0; i < 4; ++i)
        tile[ty + i * 8][tx] = src[(size_t)(r0 + ty + i * 8) * C + c0 + tx];
    __syncthreads();
#pragma unroll
    for (int i = 0; i < 4; ++i)
        dst[(size_t)(c0 + ty + i * 8) * R + r0 + tx] = (bf16)tile[tx][ty + i * 8];
}

__launch_bounds__(256)
__global__ void wtrans(const float* __restrict__ src, bf16* __restrict__ dst, int R, int C)
{
    trans_tile32(src, dst, R, C, blockIdx.y * 32, blockIdx.x * 32, threadIdx.x);
}

__launch_bounds__(256)
__global__ void wtrans_layer(const float* __restrict__ Wq, const float* __restrict__ Wk,
                             const float* __restrict__ Wv, const float* __restrict__ Wo,
                             const float* __restrict__ Wf1, const float* __restrict__ Wf2,
                             int l, bf16* __restrict__ qkvT, bf16* __restrict__ oT,
                             bf16* __restrict__ f1T, bf16* __restrict__ f2T)
{
    const int id = blockIdx.x;
    const float* src;
    bf16* dst;
    int R, C, r0, c0;
    if (id < 3072) {
        const int f = id >> 10, t = id & 1023;
        src = (f == 0 ? Wq : (f == 1 ? Wk : Wv)) + (size_t)l * 1048576;
        dst = qkvT + (size_t)f * 1048576;
        R = 1024; C = 1024; r0 = (t >> 5) * 32; c0 = (t & 31) * 32;
    } else if (id < 4096) {
        const int t = id - 3072;
        src = Wo + (size_t)l * 1048576; dst = oT;
        R = 1024; C = 1024; r0 = (t >> 5) * 32; c0 = (t & 31) * 32;
    } else if (id < 8192) {
        const int t = id - 4096;
        src = Wf1 + (size_t)l * 4194304; dst = f1T;
        R = 1024; C = 4096; r0 = (t >> 7) * 32; c0 = (t & 127) * 32;
    } else {
        const int t = id - 8192;
        src = Wf2 + (size_t)l * 4194304; dst = f2T;
        R = 4096; C = 1024; r0 = (t >> 5) * 32; c0 = (t & 31) * 32;
    }
    trans_tile32(src, dst, R, C, r0, c0, threadIdx.x);
}

// ---------------------------------------------------------------- small utils
__launch_bounds__(256)
__global__ void packb_kernel(const float* __restrict__ bq, const float* __restrict__ bk,
                             const float* __restrict__ bv, float* __restrict__ bqkv)
{
    const int id = blockIdx.x * 256 + threadIdx.x;
    if (id >= 12 * 3072) return;
    const int l = id / 3072, j = id - l * 3072;
    float v;
    if (j < 1024) v = bq[l * 1024 + j];
    else if (j < 2048) v = bk[l * 1024 + j - 1024];
    else v = bv[l * 1024 + j - 2048];
    bqkv[id] = v;
}

__launch_bounds__(256)
__global__ void cvt_kernel(const float* __restrict__ in, bf16* __restrict__ out)
{
    const int id = blockIdx.x * 256 + threadIdx.x;
    float4 v = ((const float4*)in)[id];
    bf16x4 o;
    o[0] = (bf16)v.x; o[1] = (bf16)v.y; o[2] = (bf16)v.z; o[3] = (bf16)v.w;
    ((bf16x4*)out)[id] = o;
}

// ---------------------------------------------------------------- launcher
extern "C" void kernel_launch(void* const* d_in, const int* in_sizes, int n_in,
                              void* d_out, int out_size, void* d_ws, size_t ws_size,
                              hipStream_t stream)
{
    const float* segments  = (const float*)d_in[0];
    const float* durations = (const float*)d_in[1];
    const int*   pmask     = (const int*)d_in[2];
    const float* Wproj = (const float*)d_in[3];
    const float* bproj = (const float*)d_in[4];
    const float* Wdur  = (const float*)d_in[5];
    const float* bdur  = (const float*)d_in[6];
    const float* ln1_g = (const float*)d_in[7];
    const float* ln1_b = (const float*)d_in[8];
    const float* Wq = (const float*)d_in[9];
    const float* bq = (const float*)d_in[10];
    const float* Wk = (const float*)d_in[11];
    const float* bk = (const float*)d_in[12];
    const float* Wv = (const float*)d_in[13];
    const float* bv = (const float*)d_in[14];
    const float* Wo = (const float*)d_in[15];
    const float* bo = (const float*)d_in[16];
    const float* ln2_g = (const float*)d_in[17];
    const float* ln2_b = (const float*)d_in[18];
    const float* Wff1 = (const float*)d_in[19];
    const float* bff1 = (const float*)d_in[20];
    const float* Wff2 = (const float*)d_in[21];
    const float* bff2 = (const float*)d_in[22];

    char* ws = (char*)d_ws;
    size_t off = 0;
    auto alloc = [&](size_t n) { char* p = ws + off; off += (n + 255) & ~(size_t)255; return p; };
    bf16* qkvT  = (bf16*)alloc((size_t)3072 * 1024 * 2);
    bf16* oT    = (bf16*)alloc((size_t)1024 * 1024 * 2);
    bf16* f1T   = (bf16*)alloc((size_t)4096 * 1024 * 2);
    bf16* f2T   = (bf16*)alloc((size_t)1024 * 4096 * 2);
    bf16* projT = (bf16*)alloc((size_t)1024 * 768 * 2);
    float* bqkv = (float*)alloc((size_t)12 * 3072 * 4);
    bf16* segsB = (bf16*)alloc((size_t)2048 * 768 * 2);
    float* x    = (float*)alloc((size_t)2048 * 1024 * 4);
    bf16* hbuf  = (bf16*)alloc((size_t)2048 * 1024 * 2);
    bf16* qkv   = (bf16*)alloc((size_t)2048 * 3072 * 2);
    bf16* vTb   = (bf16*)alloc((size_t)64 * 64 * 512 * 2);
    bf16* attnO = (bf16*)alloc((size_t)2048 * 1024 * 2);
    bf16* ffh   = (bf16*)alloc((size_t)2048 * 4096 * 2);
    float* xout = (float*)d_out;

    dim3 blk(256);
    wtrans<<<dim3(32, 24, 1), blk, 0, stream>>>(Wproj, projT, 768, 1024);
    packb_kernel<<<dim3(144), blk, 0, stream>>>(bq, bk, bv, bqkv);
    cvt_kernel<<<dim3(1536), blk, 0, stream>>>(segments, segsB);
    // embed: x = segs @ Wproj + bproj + dur*Wdur + bdur
    gemm_bt<3><<<dim3(8, 16), blk, 0, stream>>>(segsB, projT, bproj, 768, 1024,
                                                x, nullptr, nullptr, bdur, durations, Wdur);
    for (int l = 0; l < 12; ++l) {
        wtrans_layer<<<dim3(12288), blk, 0, stream>>>(Wq, Wk, Wv, Wo, Wff1, Wff2, l,
                                                      qkvT, oT, f1T, f2T);
        ln_kernel<<<dim3(2048), blk, 0, stream>>>(x, ln1_g + l * 1024, ln1_b + l * 1024, hbuf);
        gemm_bt<0><<<dim3(24, 16), blk, 0, stream>>>(hbuf, qkvT, bqkv + l * 3072, 1024, 3072,
                                                     nullptr, qkv, nullptr, nullptr, nullptr, nullptr);
        rope_kernel<<<dim3(8192), blk, 0, stream>>>(qkv);
        vt_kernel<<<dim3(16, 2, 64), blk, 0, stream>>>(qkv, vTb);
        attn_kernel<<<dim3(4, 16, 4), blk, 0, stream>>>(qkv, vTb, pmask, attnO);
        gemm_bt<2><<<dim3(8, 16), blk, 0, stream>>>(attnO, oT, bo + l * 1024, 1024, 1024,
                                                    x, nullptr, x, nullptr, nullptr, nullptr);
        ln_kernel<<<dim3(2048), blk, 0, stream>>>(x, ln2_g + l * 1024, ln2_b + l * 1024, hbuf);
        gemm_bt<1><<<dim3(32, 16), blk, 0, stream>>>(hbuf, f1T, bff1 + l * 4096, 1024, 4096,
                                                     nullptr, ffh, nullptr, nullptr, nullptr, nullptr);
        float* xo = (l == 11) ? xout : x;
        gemm_bt<2><<<dim3(8, 16), blk, 0, stream>>>(ffh, f2T, bff2 + l * 1024, 4096, 1024,
                                                    xo, nullptr, x, nullptr, nullptr, nullptr);
    }
}